// Round 1
// baseline (11835.547 us; speedup 1.0000x reference)
//
#include <hip/hip_runtime.h>

// GIN: 3 layers of {segment_sum aggregate, (1+eps)*x + agg, MLP(2x GEMM128 + BN + ReLU)},
// then lin1(128->128)+ReLU, lin2(128->10), log_softmax.
// N=100000, E=1.6M, all fp32.

// ---------------------------------------------------------------------------
// Detect whether edge_index is int64 (all high words zero) or int32.
__global__ void detect_idx_kernel(const unsigned int* __restrict__ w, long long nOdd,
                                  int* __restrict__ flag) {
    __shared__ int any;
    if (threadIdx.x == 0) any = 0;
    __syncthreads();
    for (long long i = threadIdx.x; i < nOdd; i += blockDim.x) {
        if (w[2 * i + 1] != 0u) { any = 1; break; }
    }
    __syncthreads();
    if (threadIdx.x == 0) *flag = (any == 0) ? 1 : 0;   // 1 => int64 layout
}

// ---------------------------------------------------------------------------
// T = (1 + eps[layer]) * x        (vectorized float4, grid-stride)
__global__ void init_scale_kernel(float* __restrict__ out, const float* __restrict__ x,
                                  const float* __restrict__ eps, int layer, long long n4) {
    float s = 1.0f + eps[layer];
    long long i = (long long)blockIdx.x * blockDim.x + threadIdx.x;
    long long stride = (long long)gridDim.x * blockDim.x;
    const float4* x4 = (const float4*)x;
    float4* o4 = (float4*)out;
    for (; i < n4; i += stride) {
        float4 v = x4[i];
        o4[i] = make_float4(s * v.x, s * v.y, s * v.z, s * v.w);
    }
}

// ---------------------------------------------------------------------------
// agg[dst[e]][:] += x[src[e]][:]   one 32-thread group per edge, float4/thread
__global__ void scatter_kernel(float* __restrict__ agg, const float* __restrict__ x,
                               const void* __restrict__ idx, long long E,
                               const int* __restrict__ flag) {
    long long gid = (long long)blockIdx.x * blockDim.x + threadIdx.x;
    long long e = gid >> 5;
    if (e >= E) return;
    int f4 = (int)(gid & 31) * 4;
    long long s, d;
    if (*flag) {
        const long long* p = (const long long*)idx;
        s = p[e]; d = p[E + e];
    } else {
        const int* p = (const int*)idx;
        s = (long long)p[e]; d = (long long)p[E + e];
    }
    const float4 v = *(const float4*)(x + s * 128 + f4);
    float* a = agg + d * 128 + f4;
    atomicAdd(a + 0, v.x);
    atomicAdd(a + 1, v.y);
    atomicAdd(a + 2, v.z);
    atomicAdd(a + 3, v.w);
}

// ---------------------------------------------------------------------------
// out = relu( (in @ W + bias) folded-BN )   [N,128] @ [128,128]
// One row per wave; W staged in LDS; BN folded to per-column scale/shift.
// If g == nullptr: scale = 1, shift = bias (plain linear + ReLU).
// Safe for out == in (row fully loaded into registers before stores).
__global__ __launch_bounds__(512) void gemm_bn_relu_kernel(
    const float* in, const float* __restrict__ W,
    const float* __restrict__ bias, const float* __restrict__ g,
    const float* __restrict__ bb, const float* __restrict__ m,
    const float* __restrict__ vv, float* out, int N) {
    __shared__ float Wl[128 * 128];
    __shared__ float sc_s[128];
    __shared__ float sh_s[128];
    for (int i = threadIdx.x; i < 128 * 128 / 4; i += blockDim.x)
        ((float4*)Wl)[i] = ((const float4*)W)[i];
    if (threadIdx.x < 128) {
        int c = threadIdx.x;
        float sc, sh;
        if (g != nullptr) {
            sc = g[c] * rsqrtf(vv[c] + 1e-5f);
            sh = bias[c] * sc + bb[c] - m[c] * sc;
        } else {
            sc = 1.0f;
            sh = bias[c];
        }
        sc_s[c] = sc;
        sh_s[c] = sh;
    }
    __syncthreads();
    int wave = threadIdx.x >> 6;
    int lane = threadIdx.x & 63;
    int wid = blockIdx.x * 8 + wave;
    int nw = gridDim.x * 8;
    for (int row = wid; row < N; row += nw) {
        const float* ir = in + (long long)row * 128;
        float r0 = ir[lane];
        float r1 = ir[lane + 64];
        float a0 = 0.f, a1 = 0.f;
#pragma unroll
        for (int k = 0; k < 64; ++k) {
            float a = __shfl(r0, k);
            a0 = fmaf(a, Wl[k * 128 + lane], a0);
            a1 = fmaf(a, Wl[k * 128 + 64 + lane], a1);
        }
#pragma unroll
        for (int k = 0; k < 64; ++k) {
            float a = __shfl(r1, k);
            a0 = fmaf(a, Wl[(64 + k) * 128 + lane], a0);
            a1 = fmaf(a, Wl[(64 + k) * 128 + 64 + lane], a1);
        }
        float* orow = out + (long long)row * 128;
        orow[lane]      = fmaxf(fmaf(a0, sc_s[lane],      sh_s[lane]),      0.f);
        orow[lane + 64] = fmaxf(fmaf(a1, sc_s[lane + 64], sh_s[lane + 64]), 0.f);
    }
}

// ---------------------------------------------------------------------------
// logits = in @ W[128,10] + b; out = log_softmax(logits). One row per wave.
__global__ __launch_bounds__(256) void head_kernel(
    const float* __restrict__ in, const float* __restrict__ W,
    const float* __restrict__ b, float* __restrict__ out, int N) {
    __shared__ float Wl[128 * 10];
    __shared__ float bl[10];
    for (int i = threadIdx.x; i < 1280; i += blockDim.x) Wl[i] = W[i];
    if (threadIdx.x < 10) bl[threadIdx.x] = b[threadIdx.x];
    __syncthreads();
    int wave = threadIdx.x >> 6;
    int lane = threadIdx.x & 63;
    int wid = blockIdx.x * 4 + wave;
    int nw = gridDim.x * 4;
    for (int row = wid; row < N; row += nw) {
        const float* ir = in + (long long)row * 128;
        float h0 = ir[lane];
        float h1 = ir[lane + 64];
        float logit[10];
#pragma unroll
        for (int c = 0; c < 10; ++c) {
            float p = h0 * Wl[lane * 10 + c] + h1 * Wl[(lane + 64) * 10 + c];
#pragma unroll
            for (int off = 32; off > 0; off >>= 1) p += __shfl_down(p, off);
            logit[c] = p;  // valid on lane 0
        }
        if (lane == 0) {
            float mx = -1e30f;
#pragma unroll
            for (int c = 0; c < 10; ++c) {
                logit[c] += bl[c];
                mx = fmaxf(mx, logit[c]);
            }
            float sum = 0.f;
#pragma unroll
            for (int c = 0; c < 10; ++c) sum += expf(logit[c] - mx);
            float lse = mx + logf(sum);
            float* orow = out + (long long)row * 10;
#pragma unroll
            for (int c = 0; c < 10; ++c) orow[c] = logit[c] - lse;
        }
    }
}

// ---------------------------------------------------------------------------
extern "C" void kernel_launch(void* const* d_in, const int* in_sizes, int n_in,
                              void* d_out, int out_size, void* d_ws, size_t ws_size,
                              hipStream_t stream) {
    const float* x   = (const float*)d_in[0];
    const void*  eix = d_in[1];
    const float* eps = (const float*)d_in[2];
    const float* W1  = (const float*)d_in[3];
    const float* b1  = (const float*)d_in[4];
    const float* g1  = (const float*)d_in[5];
    const float* bb1 = (const float*)d_in[6];
    const float* m1  = (const float*)d_in[7];
    const float* v1  = (const float*)d_in[8];
    const float* W2  = (const float*)d_in[9];
    const float* b2  = (const float*)d_in[10];
    const float* g2  = (const float*)d_in[11];
    const float* bb2 = (const float*)d_in[12];
    const float* m2  = (const float*)d_in[13];
    const float* v2  = (const float*)d_in[14];
    const float* l1W = (const float*)d_in[15];
    const float* l1b = (const float*)d_in[16];
    const float* l2W = (const float*)d_in[17];
    const float* l2b = (const float*)d_in[18];

    const int N = in_sizes[0] / 128;
    const long long E = in_sizes[1] / 2;

    float* bufT = (float*)d_ws;
    float* bufX = bufT + (size_t)N * 128;
    int*   flag = (int*)(bufX + (size_t)N * 128);

    detect_idx_kernel<<<1, 256, 0, stream>>>((const unsigned int*)eix,
                                             (E < 2048 ? E : 2048), flag);

    const long long n4 = (long long)N * 32;          // float4 count
    const int initBlocks = (int)((n4 + 255) / 256);
    const long long sThreads = E * 32;
    const int sBlocks = (int)((sThreads + 255) / 256);

    const float* cur = x;
    for (int l = 0; l < 3; ++l) {
        init_scale_kernel<<<initBlocks, 256, 0, stream>>>(bufT, cur, eps, l, n4);
        scatter_kernel<<<sBlocks, 256, 0, stream>>>(bufT, cur, eix, E, flag);
        gemm_bn_relu_kernel<<<512, 512, 0, stream>>>(
            bufT, W1 + (size_t)l * 16384, b1 + l * 128, g1 + l * 128, bb1 + l * 128,
            m1 + l * 128, v1 + l * 128, bufT, N);
        gemm_bn_relu_kernel<<<512, 512, 0, stream>>>(
            bufT, W2 + (size_t)l * 16384, b2 + l * 128, g2 + l * 128, bb2 + l * 128,
            m2 + l * 128, v2 + l * 128, bufX, N);
        cur = bufX;
    }
    // lin1 + ReLU (no BN): scale=1, shift=bias
    gemm_bn_relu_kernel<<<512, 512, 0, stream>>>(
        cur, l1W, l1b, nullptr, nullptr, nullptr, nullptr, bufT, N);
    // lin2 + log_softmax
    head_kernel<<<4096, 256, 0, stream>>>(bufT, l2W, l2b, (float*)d_out, N);
}

// Round 2
// 4537.523 us; speedup vs baseline: 2.6084x; 2.6084x over previous
//
#include <hip/hip_runtime.h>

// GIN: 3 layers of {CSR-gather aggregate fused with (1+eps)*x, MLP(2x GEMM128 + BN + ReLU)},
// then lin1(128->128)+ReLU, lin2(128->10), log_softmax.
// N=100000, E=1.6M, all fp32.
//
// Round 2: scatter (float atomics, 3.28 GB HBM write each) replaced by on-device
// CSR build + register-accumulating gather (zero float atomics).

// ---------------------------------------------------------------------------
// Detect whether edge_index is int64 (all high words zero) or int32.
__global__ void detect_idx_kernel(const unsigned int* __restrict__ w, long long nOdd,
                                  int* __restrict__ flag) {
    __shared__ int any;
    if (threadIdx.x == 0) any = 0;
    __syncthreads();
    for (long long i = threadIdx.x; i < nOdd; i += blockDim.x) {
        if (w[2 * i + 1] != 0u) { any = 1; break; }
    }
    __syncthreads();
    if (threadIdx.x == 0) *flag = (any == 0) ? 1 : 0;   // 1 => int64 layout
}

// ---------------------------------------------------------------------------
// deg[dst[e]] += 1
__global__ void hist_kernel(const void* __restrict__ idx, long long E,
                            const int* __restrict__ flag, int* __restrict__ deg) {
    long long i = (long long)blockIdx.x * blockDim.x + threadIdx.x;
    long long stride = (long long)gridDim.x * blockDim.x;
    if (*flag) {
        const long long* p = (const long long*)idx + E;   // dst half
        for (; i < E; i += stride) atomicAdd(&deg[(int)p[i]], 1);
    } else {
        const int* p = (const int*)idx + E;
        for (; i < E; i += stride) atomicAdd(&deg[p[i]], 1);
    }
}

// ---------------------------------------------------------------------------
// Exclusive scan of deg -> row_ptr (and cursor copy). Single block, 1024 thr.
__global__ __launch_bounds__(1024) void scan_kernel(const int* __restrict__ deg,
                                                    int* __restrict__ row_ptr,
                                                    int* __restrict__ cursor, int N) {
    __shared__ int part[1024];
    int t = threadIdx.x;
    int chunk = (N + 1023) / 1024;
    int lo = t * chunk;
    int hi = lo + chunk; if (hi > N) hi = N; if (lo > N) lo = N;
    int s = 0;
    for (int i = lo; i < hi; ++i) s += deg[i];
    part[t] = s;
    __syncthreads();
    for (int off = 1; off < 1024; off <<= 1) {
        int v = (t >= off) ? part[t - off] : 0;
        __syncthreads();
        part[t] += v;
        __syncthreads();
    }
    int base = (t == 0) ? 0 : part[t - 1];
    for (int i = lo; i < hi; ++i) {
        row_ptr[i] = base;
        cursor[i] = base;
        base += deg[i];
    }
    if (t == 1023) row_ptr[N] = base;
}

// ---------------------------------------------------------------------------
// csr_src[cursor[dst[e]]++] = src[e]
__global__ void fill_kernel(const void* __restrict__ idx, long long E,
                            const int* __restrict__ flag, int* __restrict__ cursor,
                            int* __restrict__ csr_src) {
    long long i = (long long)blockIdx.x * blockDim.x + threadIdx.x;
    long long stride = (long long)gridDim.x * blockDim.x;
    if (*flag) {
        const long long* ps = (const long long*)idx;
        const long long* pd = ps + E;
        for (; i < E; i += stride) {
            int pos = atomicAdd(&cursor[(int)pd[i]], 1);
            csr_src[pos] = (int)ps[i];
        }
    } else {
        const int* ps = (const int*)idx;
        const int* pd = ps + E;
        for (; i < E; i += stride) {
            int pos = atomicAdd(&cursor[pd[i]], 1);
            csr_src[pos] = ps[i];
        }
    }
}

// ---------------------------------------------------------------------------
// out[n] = (1+eps)*x[n] + sum_{j in row_ptr[n]..row_ptr[n+1]} x[csr_src[j]]
// One wave per node, float2 per lane (64 lanes * 8B = 512B/row, coalesced).
__global__ __launch_bounds__(256) void gather_kernel(
    float* __restrict__ out, const float* __restrict__ x,
    const int* __restrict__ row_ptr, const int* __restrict__ csr,
    const float* __restrict__ eps, int layer, int N) {
    int wave = threadIdx.x >> 6;
    int lane = threadIdx.x & 63;
    int wid = blockIdx.x * 4 + wave;
    int nw = gridDim.x * 4;
    float s = 1.0f + eps[layer];
    for (int n = wid; n < N; n += nw) {
        float2 acc = ((const float2*)(x + (long long)n * 128))[lane];
        acc.x *= s; acc.y *= s;
        int beg = row_ptr[n], end = row_ptr[n + 1];
        int j = beg;
        for (; j + 1 < end; j += 2) {
            int s0 = csr[j], s1 = csr[j + 1];
            float2 v0 = ((const float2*)(x + (long long)s0 * 128))[lane];
            float2 v1 = ((const float2*)(x + (long long)s1 * 128))[lane];
            acc.x += v0.x + v1.x;
            acc.y += v0.y + v1.y;
        }
        if (j < end) {
            float2 v = ((const float2*)(x + (long long)csr[j] * 128))[lane];
            acc.x += v.x;
            acc.y += v.y;
        }
        ((float2*)(out + (long long)n * 128))[lane] = acc;
    }
}

// ---------------------------------------------------------------------------
// out = relu( (in @ W + bias) folded-BN )   [N,128] @ [128,128]
// One row per wave; W staged in LDS; BN folded to per-column scale/shift.
// If g == nullptr: scale = 1, shift = bias (plain linear + ReLU).
// Safe for out == in (row fully loaded into registers before stores).
__global__ __launch_bounds__(512) void gemm_bn_relu_kernel(
    const float* in, const float* __restrict__ W,
    const float* __restrict__ bias, const float* __restrict__ g,
    const float* __restrict__ bb, const float* __restrict__ m,
    const float* __restrict__ vv, float* out, int N) {
    __shared__ float Wl[128 * 128];
    __shared__ float sc_s[128];
    __shared__ float sh_s[128];
    for (int i = threadIdx.x; i < 128 * 128 / 4; i += blockDim.x)
        ((float4*)Wl)[i] = ((const float4*)W)[i];
    if (threadIdx.x < 128) {
        int c = threadIdx.x;
        float sc, sh;
        if (g != nullptr) {
            sc = g[c] * rsqrtf(vv[c] + 1e-5f);
            sh = bias[c] * sc + bb[c] - m[c] * sc;
        } else {
            sc = 1.0f;
            sh = bias[c];
        }
        sc_s[c] = sc;
        sh_s[c] = sh;
    }
    __syncthreads();
    int wave = threadIdx.x >> 6;
    int lane = threadIdx.x & 63;
    int wid = blockIdx.x * 8 + wave;
    int nw = gridDim.x * 8;
    for (int row = wid; row < N; row += nw) {
        const float* ir = in + (long long)row * 128;
        float r0 = ir[lane];
        float r1 = ir[lane + 64];
        float a0 = 0.f, a1 = 0.f;
#pragma unroll
        for (int k = 0; k < 64; ++k) {
            float a = __shfl(r0, k);
            a0 = fmaf(a, Wl[k * 128 + lane], a0);
            a1 = fmaf(a, Wl[k * 128 + 64 + lane], a1);
        }
#pragma unroll
        for (int k = 0; k < 64; ++k) {
            float a = __shfl(r1, k);
            a0 = fmaf(a, Wl[(64 + k) * 128 + lane], a0);
            a1 = fmaf(a, Wl[(64 + k) * 128 + 64 + lane], a1);
        }
        float* orow = out + (long long)row * 128;
        orow[lane]      = fmaxf(fmaf(a0, sc_s[lane],      sh_s[lane]),      0.f);
        orow[lane + 64] = fmaxf(fmaf(a1, sc_s[lane + 64], sh_s[lane + 64]), 0.f);
    }
}

// ---------------------------------------------------------------------------
// logits = in @ W[128,10] + b; out = log_softmax(logits). One row per wave.
__global__ __launch_bounds__(256) void head_kernel(
    const float* __restrict__ in, const float* __restrict__ W,
    const float* __restrict__ b, float* __restrict__ out, int N) {
    __shared__ float Wl[128 * 10];
    __shared__ float bl[10];
    for (int i = threadIdx.x; i < 1280; i += blockDim.x) Wl[i] = W[i];
    if (threadIdx.x < 10) bl[threadIdx.x] = b[threadIdx.x];
    __syncthreads();
    int wave = threadIdx.x >> 6;
    int lane = threadIdx.x & 63;
    int wid = blockIdx.x * 4 + wave;
    int nw = gridDim.x * 4;
    for (int row = wid; row < N; row += nw) {
        const float* ir = in + (long long)row * 128;
        float h0 = ir[lane];
        float h1 = ir[lane + 64];
        float logit[10];
#pragma unroll
        for (int c = 0; c < 10; ++c) {
            float p = h0 * Wl[lane * 10 + c] + h1 * Wl[(lane + 64) * 10 + c];
#pragma unroll
            for (int off = 32; off > 0; off >>= 1) p += __shfl_down(p, off);
            logit[c] = p;  // valid on lane 0
        }
        if (lane == 0) {
            float mx = -1e30f;
#pragma unroll
            for (int c = 0; c < 10; ++c) {
                logit[c] += bl[c];
                mx = fmaxf(mx, logit[c]);
            }
            float sum = 0.f;
#pragma unroll
            for (int c = 0; c < 10; ++c) sum += expf(logit[c] - mx);
            float lse = mx + logf(sum);
            float* orow = out + (long long)row * 10;
#pragma unroll
            for (int c = 0; c < 10; ++c) orow[c] = logit[c] - lse;
        }
    }
}

// ---------------------------------------------------------------------------
extern "C" void kernel_launch(void* const* d_in, const int* in_sizes, int n_in,
                              void* d_out, int out_size, void* d_ws, size_t ws_size,
                              hipStream_t stream) {
    const float* x   = (const float*)d_in[0];
    const void*  eix = d_in[1];
    const float* eps = (const float*)d_in[2];
    const float* W1  = (const float*)d_in[3];
    const float* b1  = (const float*)d_in[4];
    const float* g1  = (const float*)d_in[5];
    const float* bb1 = (const float*)d_in[6];
    const float* m1  = (const float*)d_in[7];
    const float* v1  = (const float*)d_in[8];
    const float* W2  = (const float*)d_in[9];
    const float* b2  = (const float*)d_in[10];
    const float* g2  = (const float*)d_in[11];
    const float* bb2 = (const float*)d_in[12];
    const float* m2  = (const float*)d_in[13];
    const float* v2  = (const float*)d_in[14];
    const float* l1W = (const float*)d_in[15];
    const float* l1b = (const float*)d_in[16];
    const float* l2W = (const float*)d_in[17];
    const float* l2b = (const float*)d_in[18];

    const int N = in_sizes[0] / 128;
    const long long E = in_sizes[1] / 2;

    // workspace layout
    float* bufA = (float*)d_ws;                        // N*128 f32
    float* bufB = bufA + (size_t)N * 128;              // N*128 f32
    int* deg     = (int*)(bufB + (size_t)N * 128);     // N (also reused)
    int* row_ptr = deg + N;                            // N+1
    int* cursor  = row_ptr + N + 1;                    // N
    int* csr_src = cursor + N;                         // E
    int* flag    = csr_src + E;                        // 1

    detect_idx_kernel<<<1, 256, 0, stream>>>((const unsigned int*)eix,
                                             (E < 2048 ? E : 2048), flag);
    hipMemsetAsync(deg, 0, (size_t)N * sizeof(int), stream);

    const int eBlocks = 2048;
    hist_kernel<<<eBlocks, 256, 0, stream>>>(eix, E, flag, deg);
    scan_kernel<<<1, 1024, 0, stream>>>(deg, row_ptr, cursor, N);
    fill_kernel<<<eBlocks, 256, 0, stream>>>(eix, E, flag, cursor, csr_src);

    const int gBlocks = 2048;   // 8192 waves, grid-stride over nodes

    const float* cur = x;
    float* nxt = bufA;
    float* other = bufB;
    for (int l = 0; l < 3; ++l) {
        gather_kernel<<<gBlocks, 256, 0, stream>>>(nxt, cur, row_ptr, csr_src, eps, l, N);
        gemm_bn_relu_kernel<<<512, 512, 0, stream>>>(
            nxt, W1 + (size_t)l * 16384, b1 + l * 128, g1 + l * 128, bb1 + l * 128,
            m1 + l * 128, v1 + l * 128, nxt, N);
        gemm_bn_relu_kernel<<<512, 512, 0, stream>>>(
            nxt, W2 + (size_t)l * 16384, b2 + l * 128, g2 + l * 128, bb2 + l * 128,
            m2 + l * 128, v2 + l * 128, nxt, N);
        cur = nxt;
        nxt = other;
        other = (float*)cur;
    }
    // lin1 + ReLU (no BN): scale=1, shift=bias
    gemm_bn_relu_kernel<<<512, 512, 0, stream>>>(
        cur, l1W, l1b, nullptr, nullptr, nullptr, nullptr, nxt, N);
    // lin2 + log_softmax
    head_kernel<<<4096, 256, 0, stream>>>(nxt, l2W, l2b, (float*)d_out, N);
}

// Round 3
// 1252.222 us; speedup vs baseline: 9.4516x; 3.6236x over previous
//
#include <hip/hip_runtime.h>

// GIN: 3 layers of {CSR-gather aggregate fused with (1+eps)*x, MLP(2x GEMM128 + BN + ReLU)},
// then lin1(128->128)+ReLU, lin2(128->10), log_softmax.
// N=100000, E=1.6M, all fp32.
//
// Round 3: shfl-broadcast GEMM (542us, 935MB fetch, VALUBusy 10%) replaced by a
// register-tiled GEMM: 256x128 tile/block, K chunked by 32 via LDS, 8x16 acc/thread,
// XOR-swizzled input tile + padded W tile for conflict-free ds_read_b128.

// ---------------------------------------------------------------------------
// Detect whether edge_index is int64 (all high words zero) or int32.
__global__ void detect_idx_kernel(const unsigned int* __restrict__ w, long long nOdd,
                                  int* __restrict__ flag) {
    __shared__ int any;
    if (threadIdx.x == 0) any = 0;
    __syncthreads();
    for (long long i = threadIdx.x; i < nOdd; i += blockDim.x) {
        if (w[2 * i + 1] != 0u) { any = 1; break; }
    }
    __syncthreads();
    if (threadIdx.x == 0) *flag = (any == 0) ? 1 : 0;   // 1 => int64 layout
}

// ---------------------------------------------------------------------------
// deg[dst[e]] += 1
__global__ void hist_kernel(const void* __restrict__ idx, long long E,
                            const int* __restrict__ flag, int* __restrict__ deg) {
    long long i = (long long)blockIdx.x * blockDim.x + threadIdx.x;
    long long stride = (long long)gridDim.x * blockDim.x;
    if (*flag) {
        const long long* p = (const long long*)idx + E;   // dst half
        for (; i < E; i += stride) atomicAdd(&deg[(int)p[i]], 1);
    } else {
        const int* p = (const int*)idx + E;
        for (; i < E; i += stride) atomicAdd(&deg[p[i]], 1);
    }
}

// ---------------------------------------------------------------------------
// Exclusive scan of deg -> row_ptr (and cursor copy). Single block, 1024 thr.
__global__ __launch_bounds__(1024) void scan_kernel(const int* __restrict__ deg,
                                                    int* __restrict__ row_ptr,
                                                    int* __restrict__ cursor, int N) {
    __shared__ int part[1024];
    int t = threadIdx.x;
    int chunk = (N + 1023) / 1024;
    int lo = t * chunk;
    int hi = lo + chunk; if (hi > N) hi = N; if (lo > N) lo = N;
    int s = 0;
    for (int i = lo; i < hi; ++i) s += deg[i];
    part[t] = s;
    __syncthreads();
    for (int off = 1; off < 1024; off <<= 1) {
        int v = (t >= off) ? part[t - off] : 0;
        __syncthreads();
        part[t] += v;
        __syncthreads();
    }
    int base = (t == 0) ? 0 : part[t - 1];
    for (int i = lo; i < hi; ++i) {
        row_ptr[i] = base;
        cursor[i] = base;
        base += deg[i];
    }
    if (t == 1023) row_ptr[N] = base;
}

// ---------------------------------------------------------------------------
// csr_src[cursor[dst[e]]++] = src[e]
__global__ void fill_kernel(const void* __restrict__ idx, long long E,
                            const int* __restrict__ flag, int* __restrict__ cursor,
                            int* __restrict__ csr_src) {
    long long i = (long long)blockIdx.x * blockDim.x + threadIdx.x;
    long long stride = (long long)gridDim.x * blockDim.x;
    if (*flag) {
        const long long* ps = (const long long*)idx;
        const long long* pd = ps + E;
        for (; i < E; i += stride) {
            int pos = atomicAdd(&cursor[(int)pd[i]], 1);
            csr_src[pos] = (int)ps[i];
        }
    } else {
        const int* ps = (const int*)idx;
        const int* pd = ps + E;
        for (; i < E; i += stride) {
            int pos = atomicAdd(&cursor[pd[i]], 1);
            csr_src[pos] = ps[i];
        }
    }
}

// ---------------------------------------------------------------------------
// out[n] = (1+eps)*x[n] + sum_{j in row_ptr[n]..row_ptr[n+1]} x[csr_src[j]]
// One wave per node, float2 per lane (64 lanes * 8B = 512B/row, coalesced).
__global__ __launch_bounds__(256) void gather_kernel(
    float* __restrict__ out, const float* __restrict__ x,
    const int* __restrict__ row_ptr, const int* __restrict__ csr,
    const float* __restrict__ eps, int layer, int N) {
    int wave = threadIdx.x >> 6;
    int lane = threadIdx.x & 63;
    int wid = blockIdx.x * 4 + wave;
    int nw = gridDim.x * 4;
    float s = 1.0f + eps[layer];
    for (int n = wid; n < N; n += nw) {
        float2 acc = ((const float2*)(x + (long long)n * 128))[lane];
        acc.x *= s; acc.y *= s;
        int beg = row_ptr[n], end = row_ptr[n + 1];
        int j = beg;
        for (; j + 1 < end; j += 2) {
            int s0 = csr[j], s1 = csr[j + 1];
            float2 v0 = ((const float2*)(x + (long long)s0 * 128))[lane];
            float2 v1 = ((const float2*)(x + (long long)s1 * 128))[lane];
            acc.x += v0.x + v1.x;
            acc.y += v0.y + v1.y;
        }
        if (j < end) {
            float2 v = ((const float2*)(x + (long long)csr[j] * 128))[lane];
            acc.x += v.x;
            acc.y += v.y;
        }
        ((float2*)(out + (long long)n * 128))[lane] = acc;
    }
}

// ---------------------------------------------------------------------------
// out = relu( (in @ W + bias) folded-BN )   [N,128] @ [128,128]
// 256-row x 128-col tile per block (256 thr); K in 4 chunks of 32 via LDS.
// Thread (ty=tid>>3, tx=tid&7): rows 8*ty+rr, cols 32*j+4*tx+jj -> acc[8][16].
// in-tile XOR-swizzled (k ^ ((ty&7)<<2)); W tile rows padded to 132 dwords.
// If g == nullptr: scale = 1, shift = bias (plain linear + ReLU).
// Safe for out == in: all stores happen in the epilogue, after every chunk of
// this block's rows has been staged and consumed; blocks touch disjoint rows.
__global__ __launch_bounds__(256, 2) void gemm_bn_relu_kernel(
    const float* __restrict__ in, const float* __restrict__ W,
    const float* __restrict__ bias, const float* __restrict__ g,
    const float* __restrict__ bb, const float* __restrict__ m,
    const float* __restrict__ vv, float* __restrict__ out, int N) {
    __shared__ float inL[256 * 40];    // 40KB: 256 rows x (32 k, swizzled, +8 pad)
    __shared__ float wL[32 * 132];     // 16.9KB: 32 k x (128 cols + 4 pad)
    __shared__ float sc_s[128];
    __shared__ float sh_s[128];

    const int tid = threadIdx.x;
    if (tid < 128) {
        int c = tid;
        float sc, sh;
        if (g != nullptr) {
            sc = g[c] * rsqrtf(vv[c] + 1e-5f);
            sh = bias[c] * sc + bb[c] - m[c] * sc;
        } else {
            sc = 1.0f;
            sh = bias[c];
        }
        sc_s[c] = sc;
        sh_s[c] = sh;
    }

    const int ty = tid >> 3;            // 0..31: row group (8 rows)
    const int tx = tid & 7;             // 0..7 : col group (16 cols, split 4x4)
    const int swz = (ty & 7) << 2;      // bank swizzle key for reads
    const long long base = (long long)blockIdx.x * 256;

    float acc[8][16];
#pragma unroll
    for (int r = 0; r < 8; ++r)
#pragma unroll
        for (int c = 0; c < 16; ++c) acc[r][c] = 0.f;

#pragma unroll 1
    for (int kc = 0; kc < 4; ++kc) {
        const int k0 = kc * 32;
        __syncthreads();   // previous chunk fully consumed (also covers sc_s)
        // stage input rows: thread t -> row base+t, dwords [k0, k0+32)
        {
            long long r = base + tid;
            if (r >= N) r = N - 1;                       // clamp (tail tile)
            const float4* src = (const float4*)(in + r * 128 + k0);
            const int wkey = ((tid >> 3) & 7) << 2;
            float* drow = &inL[tid * 40];
#pragma unroll
            for (int q = 0; q < 8; ++q) {
                float4 v = src[q];
                *(float4*)&drow[(q * 4) ^ wkey] = v;
            }
        }
        // stage W rows [k0, k0+32) x 128 cols
        {
            const float4* wsrc = (const float4*)(W + (size_t)k0 * 128);
#pragma unroll
            for (int q = 0; q < 4; ++q) {
                int i = tid + q * 256;                   // 0..1023 float4s
                int kk = i >> 5, c4 = i & 31;
                float4 v = wsrc[i];
                *(float4*)&wL[kk * 132 + c4 * 4] = v;
            }
        }
        __syncthreads();
        // compute 32 k for this chunk
#pragma unroll 2
        for (int k4 = 0; k4 < 8; ++k4) {
            float4 a[8];
#pragma unroll
            for (int rr = 0; rr < 8; ++rr)
                a[rr] = *(const float4*)&inL[(ty * 8 + rr) * 40 + ((k4 * 4) ^ swz)];
#pragma unroll
            for (int kk = 0; kk < 4; ++kk) {
                const int k = k4 * 4 + kk;
                const float4 w0 = *(const float4*)&wL[k * 132 + 0  + tx * 4];
                const float4 w1 = *(const float4*)&wL[k * 132 + 32 + tx * 4];
                const float4 w2 = *(const float4*)&wL[k * 132 + 64 + tx * 4];
                const float4 w3 = *(const float4*)&wL[k * 132 + 96 + tx * 4];
#pragma unroll
                for (int rr = 0; rr < 8; ++rr) {
                    const float av = (&a[rr].x)[kk];
                    acc[rr][0]  = fmaf(av, w0.x, acc[rr][0]);
                    acc[rr][1]  = fmaf(av, w0.y, acc[rr][1]);
                    acc[rr][2]  = fmaf(av, w0.z, acc[rr][2]);
                    acc[rr][3]  = fmaf(av, w0.w, acc[rr][3]);
                    acc[rr][4]  = fmaf(av, w1.x, acc[rr][4]);
                    acc[rr][5]  = fmaf(av, w1.y, acc[rr][5]);
                    acc[rr][6]  = fmaf(av, w1.z, acc[rr][6]);
                    acc[rr][7]  = fmaf(av, w1.w, acc[rr][7]);
                    acc[rr][8]  = fmaf(av, w2.x, acc[rr][8]);
                    acc[rr][9]  = fmaf(av, w2.y, acc[rr][9]);
                    acc[rr][10] = fmaf(av, w2.z, acc[rr][10]);
                    acc[rr][11] = fmaf(av, w2.w, acc[rr][11]);
                    acc[rr][12] = fmaf(av, w3.x, acc[rr][12]);
                    acc[rr][13] = fmaf(av, w3.y, acc[rr][13]);
                    acc[rr][14] = fmaf(av, w3.z, acc[rr][14]);
                    acc[rr][15] = fmaf(av, w3.w, acc[rr][15]);
                }
            }
        }
    }

    // epilogue: BN fold + ReLU + float4 stores
#pragma unroll
    for (int rr = 0; rr < 8; ++rr) {
        const long long r = base + ty * 8 + rr;
        if (r < N) {
            float* orow = out + r * 128;
#pragma unroll
            for (int j = 0; j < 4; ++j) {
                const int c = j * 32 + tx * 4;
                float4 o;
                o.x = fmaxf(fmaf(acc[rr][j * 4 + 0], sc_s[c + 0], sh_s[c + 0]), 0.f);
                o.y = fmaxf(fmaf(acc[rr][j * 4 + 1], sc_s[c + 1], sh_s[c + 1]), 0.f);
                o.z = fmaxf(fmaf(acc[rr][j * 4 + 2], sc_s[c + 2], sh_s[c + 2]), 0.f);
                o.w = fmaxf(fmaf(acc[rr][j * 4 + 3], sc_s[c + 3], sh_s[c + 3]), 0.f);
                *(float4*)&orow[c] = o;
            }
        }
    }
}

// ---------------------------------------------------------------------------
// logits = in @ W[128,10] + b; out = log_softmax(logits). One row per wave.
__global__ __launch_bounds__(256) void head_kernel(
    const float* __restrict__ in, const float* __restrict__ W,
    const float* __restrict__ b, float* __restrict__ out, int N) {
    __shared__ float Wl[128 * 10];
    __shared__ float bl[10];
    for (int i = threadIdx.x; i < 1280; i += blockDim.x) Wl[i] = W[i];
    if (threadIdx.x < 10) bl[threadIdx.x] = b[threadIdx.x];
    __syncthreads();
    int wave = threadIdx.x >> 6;
    int lane = threadIdx.x & 63;
    int wid = blockIdx.x * 4 + wave;
    int nw = gridDim.x * 4;
    for (int row = wid; row < N; row += nw) {
        const float* ir = in + (long long)row * 128;
        float h0 = ir[lane];
        float h1 = ir[lane + 64];
        float logit[10];
#pragma unroll
        for (int c = 0; c < 10; ++c) {
            float p = h0 * Wl[lane * 10 + c] + h1 * Wl[(lane + 64) * 10 + c];
#pragma unroll
            for (int off = 32; off > 0; off >>= 1) p += __shfl_down(p, off);
            logit[c] = p;  // valid on lane 0
        }
        if (lane == 0) {
            float mx = -1e30f;
#pragma unroll
            for (int c = 0; c < 10; ++c) {
                logit[c] += bl[c];
                mx = fmaxf(mx, logit[c]);
            }
            float sum = 0.f;
#pragma unroll
            for (int c = 0; c < 10; ++c) sum += expf(logit[c] - mx);
            float lse = mx + logf(sum);
            float* orow = out + (long long)row * 10;
#pragma unroll
            for (int c = 0; c < 10; ++c) orow[c] = logit[c] - lse;
        }
    }
}

// ---------------------------------------------------------------------------
extern "C" void kernel_launch(void* const* d_in, const int* in_sizes, int n_in,
                              void* d_out, int out_size, void* d_ws, size_t ws_size,
                              hipStream_t stream) {
    const float* x   = (const float*)d_in[0];
    const void*  eix = d_in[1];
    const float* eps = (const float*)d_in[2];
    const float* W1  = (const float*)d_in[3];
    const float* b1  = (const float*)d_in[4];
    const float* g1  = (const float*)d_in[5];
    const float* bb1 = (const float*)d_in[6];
    const float* m1  = (const float*)d_in[7];
    const float* v1  = (const float*)d_in[8];
    const float* W2  = (const float*)d_in[9];
    const float* b2  = (const float*)d_in[10];
    const float* g2  = (const float*)d_in[11];
    const float* bb2 = (const float*)d_in[12];
    const float* m2  = (const float*)d_in[13];
    const float* v2  = (const float*)d_in[14];
    const float* l1W = (const float*)d_in[15];
    const float* l1b = (const float*)d_in[16];
    const float* l2W = (const float*)d_in[17];
    const float* l2b = (const float*)d_in[18];

    const int N = in_sizes[0] / 128;
    const long long E = in_sizes[1] / 2;

    // workspace layout
    float* bufA = (float*)d_ws;                        // N*128 f32
    float* bufB = bufA + (size_t)N * 128;              // N*128 f32
    int* deg     = (int*)(bufB + (size_t)N * 128);     // N
    int* row_ptr = deg + N;                            // N+1
    int* cursor  = row_ptr + N + 1;                    // N
    int* csr_src = cursor + N;                         // E
    int* flag    = csr_src + E;                        // 1

    detect_idx_kernel<<<1, 256, 0, stream>>>((const unsigned int*)eix,
                                             (E < 2048 ? E : 2048), flag);
    hipMemsetAsync(deg, 0, (size_t)N * sizeof(int), stream);

    const int eBlocks = 2048;
    hist_kernel<<<eBlocks, 256, 0, stream>>>(eix, E, flag, deg);
    scan_kernel<<<1, 1024, 0, stream>>>(deg, row_ptr, cursor, N);
    fill_kernel<<<eBlocks, 256, 0, stream>>>(eix, E, flag, cursor, csr_src);

    const int gBlocks = 2048;                 // gather: 8192 waves grid-stride
    const int mBlocks = (N + 255) / 256;      // gemm tiles

    const float* cur = x;
    float* nxt = bufA;
    float* other = bufB;
    for (int l = 0; l < 3; ++l) {
        gather_kernel<<<gBlocks, 256, 0, stream>>>(nxt, cur, row_ptr, csr_src, eps, l, N);
        gemm_bn_relu_kernel<<<mBlocks, 256, 0, stream>>>(
            nxt, W1 + (size_t)l * 16384, b1 + l * 128, g1 + l * 128, bb1 + l * 128,
            m1 + l * 128, v1 + l * 128, nxt, N);
        gemm_bn_relu_kernel<<<mBlocks, 256, 0, stream>>>(
            nxt, W2 + (size_t)l * 16384, b2 + l * 128, g2 + l * 128, bb2 + l * 128,
            m2 + l * 128, v2 + l * 128, nxt, N);
        cur = nxt;
        nxt = other;
        other = (float*)cur;
    }
    // lin1 + ReLU (no BN): scale=1, shift=bias
    gemm_bn_relu_kernel<<<mBlocks, 256, 0, stream>>>(
        cur, l1W, l1b, nullptr, nullptr, nullptr, nullptr, nxt, N);
    // lin2 + log_softmax
    head_kernel<<<4096, 256, 0, stream>>>(nxt, l2W, l2b, (float*)d_out, N);
}

// Round 4
// 996.163 us; speedup vs baseline: 11.8811x; 1.2570x over previous
//
#include <hip/hip_runtime.h>

// GIN: 3 layers of {CSR-gather aggregate fused with (1+eps)*x, MLP(2x GEMM128 + BN + ReLU)},
// then lin1(128->128)+ReLU, lin2(128->10), log_softmax.
// N=100000, E=1.6M, all fp32.
//
// Round 4: single-block scan (228us, 0.15% occupancy) -> 3-phase parallel scan
// (~12us). Gather neighbor loop unrolled x4 for memory-level parallelism.

#define SCAN_BLOCKS 256

// ---------------------------------------------------------------------------
// Detect whether edge_index is int64 (all high words zero) or int32.
__global__ void detect_idx_kernel(const unsigned int* __restrict__ w, long long nOdd,
                                  int* __restrict__ flag) {
    __shared__ int any;
    if (threadIdx.x == 0) any = 0;
    __syncthreads();
    for (long long i = threadIdx.x; i < nOdd; i += blockDim.x) {
        if (w[2 * i + 1] != 0u) { any = 1; break; }
    }
    __syncthreads();
    if (threadIdx.x == 0) *flag = (any == 0) ? 1 : 0;   // 1 => int64 layout
}

// ---------------------------------------------------------------------------
// deg[dst[e]] += 1
__global__ void hist_kernel(const void* __restrict__ idx, long long E,
                            const int* __restrict__ flag, int* __restrict__ deg) {
    long long i = (long long)blockIdx.x * blockDim.x + threadIdx.x;
    long long stride = (long long)gridDim.x * blockDim.x;
    if (*flag) {
        const long long* p = (const long long*)idx + E;   // dst half
        for (; i < E; i += stride) atomicAdd(&deg[(int)p[i]], 1);
    } else {
        const int* p = (const int*)idx + E;
        for (; i < E; i += stride) atomicAdd(&deg[p[i]], 1);
    }
}

// ---------------------------------------------------------------------------
// Phase 1: per-chunk degree sums. Chunk c = ceil(N/SCAN_BLOCKS) contiguous elems.
__global__ __launch_bounds__(256) void scan_reduce_kernel(const int* __restrict__ deg,
                                                          int N, int* __restrict__ partial) {
    int b = blockIdx.x, t = threadIdx.x;
    int C = (N + SCAN_BLOCKS - 1) / SCAN_BLOCKS;
    int lo = b * C, hi = lo + C; if (hi > N) hi = N;
    int s = 0;
    for (int i = lo + t; i < hi; i += 256) s += deg[i];
    __shared__ int red[256];
    red[t] = s;
    __syncthreads();
    for (int off = 128; off > 0; off >>= 1) {
        if (t < off) red[t] += red[t + off];
        __syncthreads();
    }
    if (t == 0) partial[b] = red[0];
}

// Phase 2: exclusive scan of SCAN_BLOCKS partials (in place); row_ptr[N] = E.
__global__ __launch_bounds__(256) void scan_partials_kernel(int* __restrict__ partial,
                                                            int* __restrict__ row_ptr,
                                                            int N, long long E) {
    int t = threadIdx.x;
    __shared__ int sh[SCAN_BLOCKS];
    sh[t] = partial[t];
    __syncthreads();
    for (int off = 1; off < SCAN_BLOCKS; off <<= 1) {
        int v = (t >= off) ? sh[t - off] : 0;
        __syncthreads();
        sh[t] += v;
        __syncthreads();
    }
    partial[t] = (t == 0) ? 0 : sh[t - 1];   // exclusive
    if (t == 0) row_ptr[N] = (int)E;
}

// Phase 3: per-chunk block scan + sequential write of row_ptr/cursor.
__global__ __launch_bounds__(256) void scan_write_kernel(const int* __restrict__ deg, int N,
                                                         const int* __restrict__ partial,
                                                         int* __restrict__ row_ptr,
                                                         int* __restrict__ cursor) {
    int b = blockIdx.x, t = threadIdx.x;
    int C = (N + SCAN_BLOCKS - 1) / SCAN_BLOCKS;
    int lo = b * C, hi = lo + C; if (hi > N) hi = N;
    int sub = (C + 255) / 256;
    int s0 = lo + t * sub;
    int s1 = s0 + sub; if (s1 > hi) s1 = hi; if (s0 > hi) s0 = hi;
    int s = 0;
    for (int i = s0; i < s1; ++i) s += deg[i];
    __shared__ int sh[256];
    sh[t] = s;
    __syncthreads();
    for (int off = 1; off < 256; off <<= 1) {
        int v = (t >= off) ? sh[t - off] : 0;
        __syncthreads();
        sh[t] += v;
        __syncthreads();
    }
    int base = partial[b] + sh[t] - s;       // exclusive prefix for this thread
    for (int i = s0; i < s1; ++i) {
        row_ptr[i] = base;
        cursor[i] = base;
        base += deg[i];
    }
}

// ---------------------------------------------------------------------------
// csr_src[cursor[dst[e]]++] = src[e]
__global__ void fill_kernel(const void* __restrict__ idx, long long E,
                            const int* __restrict__ flag, int* __restrict__ cursor,
                            int* __restrict__ csr_src) {
    long long i = (long long)blockIdx.x * blockDim.x + threadIdx.x;
    long long stride = (long long)gridDim.x * blockDim.x;
    if (*flag) {
        const long long* ps = (const long long*)idx;
        const long long* pd = ps + E;
        for (; i < E; i += stride) {
            int pos = atomicAdd(&cursor[(int)pd[i]], 1);
            csr_src[pos] = (int)ps[i];
        }
    } else {
        const int* ps = (const int*)idx;
        const int* pd = ps + E;
        for (; i < E; i += stride) {
            int pos = atomicAdd(&cursor[pd[i]], 1);
            csr_src[pos] = ps[i];
        }
    }
}

// ---------------------------------------------------------------------------
// out[n] = (1+eps)*x[n] + sum_{j in row_ptr[n]..row_ptr[n+1]} x[csr_src[j]]
// One wave per node, float2 per lane; neighbor loop unrolled x4 for MLP.
__global__ __launch_bounds__(256) void gather_kernel(
    float* __restrict__ out, const float* __restrict__ x,
    const int* __restrict__ row_ptr, const int* __restrict__ csr,
    const float* __restrict__ eps, int layer, int N) {
    int wave = threadIdx.x >> 6;
    int lane = threadIdx.x & 63;
    int wid = blockIdx.x * 4 + wave;
    int nw = gridDim.x * 4;
    float s = 1.0f + eps[layer];
    for (int n = wid; n < N; n += nw) {
        float2 acc = ((const float2*)(x + (long long)n * 128))[lane];
        acc.x *= s; acc.y *= s;
        int beg = row_ptr[n], end = row_ptr[n + 1];
        int j = beg;
        for (; j + 3 < end; j += 4) {
            int s0 = csr[j], s1 = csr[j + 1], s2 = csr[j + 2], s3 = csr[j + 3];
            float2 v0 = ((const float2*)(x + (long long)s0 * 128))[lane];
            float2 v1 = ((const float2*)(x + (long long)s1 * 128))[lane];
            float2 v2 = ((const float2*)(x + (long long)s2 * 128))[lane];
            float2 v3 = ((const float2*)(x + (long long)s3 * 128))[lane];
            acc.x += (v0.x + v1.x) + (v2.x + v3.x);
            acc.y += (v0.y + v1.y) + (v2.y + v3.y);
        }
        for (; j < end; ++j) {
            float2 v = ((const float2*)(x + (long long)csr[j] * 128))[lane];
            acc.x += v.x;
            acc.y += v.y;
        }
        ((float2*)(out + (long long)n * 128))[lane] = acc;
    }
}

// ---------------------------------------------------------------------------
// out = relu( (in @ W + bias) folded-BN )   [N,128] @ [128,128]
// 256-row x 128-col tile per block (256 thr); K in 4 chunks of 32 via LDS.
// Thread (ty=tid>>3, tx=tid&7): rows 8*ty+rr, cols 32*j+4*tx+jj -> acc[8][16].
// in-tile XOR-swizzled (k ^ ((ty&7)<<2)); W tile rows padded to 132 dwords.
// If g == nullptr: scale = 1, shift = bias (plain linear + ReLU).
// Safe for out == in: each block reads only the rows it writes.
__global__ __launch_bounds__(256, 2) void gemm_bn_relu_kernel(
    const float* __restrict__ in, const float* __restrict__ W,
    const float* __restrict__ bias, const float* __restrict__ g,
    const float* __restrict__ bb, const float* __restrict__ m,
    const float* __restrict__ vv, float* __restrict__ out, int N) {
    __shared__ float inL[256 * 40];    // 40KB: 256 rows x (32 k, swizzled, +8 pad)
    __shared__ float wL[32 * 132];     // 16.9KB: 32 k x (128 cols + 4 pad)
    __shared__ float sc_s[128];
    __shared__ float sh_s[128];

    const int tid = threadIdx.x;
    if (tid < 128) {
        int c = tid;
        float sc, sh;
        if (g != nullptr) {
            sc = g[c] * rsqrtf(vv[c] + 1e-5f);
            sh = bias[c] * sc + bb[c] - m[c] * sc;
        } else {
            sc = 1.0f;
            sh = bias[c];
        }
        sc_s[c] = sc;
        sh_s[c] = sh;
    }

    const int ty = tid >> 3;            // 0..31: row group (8 rows)
    const int tx = tid & 7;             // 0..7 : col group (16 cols, split 4x4)
    const int swz = (ty & 7) << 2;      // bank swizzle key for reads
    const long long base = (long long)blockIdx.x * 256;

    float acc[8][16];
#pragma unroll
    for (int r = 0; r < 8; ++r)
#pragma unroll
        for (int c = 0; c < 16; ++c) acc[r][c] = 0.f;

#pragma unroll 1
    for (int kc = 0; kc < 4; ++kc) {
        const int k0 = kc * 32;
        __syncthreads();   // previous chunk fully consumed (also covers sc_s)
        // stage input rows: thread t -> row base+t, dwords [k0, k0+32)
        {
            long long r = base + tid;
            if (r >= N) r = N - 1;                       // clamp (tail tile)
            const float4* src = (const float4*)(in + r * 128 + k0);
            const int wkey = ((tid >> 3) & 7) << 2;
            float* drow = &inL[tid * 40];
#pragma unroll
            for (int q = 0; q < 8; ++q) {
                float4 v = src[q];
                *(float4*)&drow[(q * 4) ^ wkey] = v;
            }
        }
        // stage W rows [k0, k0+32) x 128 cols
        {
            const float4* wsrc = (const float4*)(W + (size_t)k0 * 128);
#pragma unroll
            for (int q = 0; q < 4; ++q) {
                int i = tid + q * 256;                   // 0..1023 float4s
                int kk = i >> 5, c4 = i & 31;
                float4 v = wsrc[i];
                *(float4*)&wL[kk * 132 + c4 * 4] = v;
            }
        }
        __syncthreads();
        // compute 32 k for this chunk
#pragma unroll 2
        for (int k4 = 0; k4 < 8; ++k4) {
            float4 a[8];
#pragma unroll
            for (int rr = 0; rr < 8; ++rr)
                a[rr] = *(const float4*)&inL[(ty * 8 + rr) * 40 + ((k4 * 4) ^ swz)];
#pragma unroll
            for (int kk = 0; kk < 4; ++kk) {
                const int k = k4 * 4 + kk;
                const float4 w0 = *(const float4*)&wL[k * 132 + 0  + tx * 4];
                const float4 w1 = *(const float4*)&wL[k * 132 + 32 + tx * 4];
                const float4 w2 = *(const float4*)&wL[k * 132 + 64 + tx * 4];
                const float4 w3 = *(const float4*)&wL[k * 132 + 96 + tx * 4];
#pragma unroll
                for (int rr = 0; rr < 8; ++rr) {
                    const float av = (&a[rr].x)[kk];
                    acc[rr][0]  = fmaf(av, w0.x, acc[rr][0]);
                    acc[rr][1]  = fmaf(av, w0.y, acc[rr][1]);
                    acc[rr][2]  = fmaf(av, w0.z, acc[rr][2]);
                    acc[rr][3]  = fmaf(av, w0.w, acc[rr][3]);
                    acc[rr][4]  = fmaf(av, w1.x, acc[rr][4]);
                    acc[rr][5]  = fmaf(av, w1.y, acc[rr][5]);
                    acc[rr][6]  = fmaf(av, w1.z, acc[rr][6]);
                    acc[rr][7]  = fmaf(av, w1.w, acc[rr][7]);
                    acc[rr][8]  = fmaf(av, w2.x, acc[rr][8]);
                    acc[rr][9]  = fmaf(av, w2.y, acc[rr][9]);
                    acc[rr][10] = fmaf(av, w2.z, acc[rr][10]);
                    acc[rr][11] = fmaf(av, w2.w, acc[rr][11]);
                    acc[rr][12] = fmaf(av, w3.x, acc[rr][12]);
                    acc[rr][13] = fmaf(av, w3.y, acc[rr][13]);
                    acc[rr][14] = fmaf(av, w3.z, acc[rr][14]);
                    acc[rr][15] = fmaf(av, w3.w, acc[rr][15]);
                }
            }
        }
    }

    // epilogue: BN fold + ReLU + float4 stores
#pragma unroll
    for (int rr = 0; rr < 8; ++rr) {
        const long long r = base + ty * 8 + rr;
        if (r < N) {
            float* orow = out + r * 128;
#pragma unroll
            for (int j = 0; j < 4; ++j) {
                const int c = j * 32 + tx * 4;
                float4 o;
                o.x = fmaxf(fmaf(acc[rr][j * 4 + 0], sc_s[c + 0], sh_s[c + 0]), 0.f);
                o.y = fmaxf(fmaf(acc[rr][j * 4 + 1], sc_s[c + 1], sh_s[c + 1]), 0.f);
                o.z = fmaxf(fmaf(acc[rr][j * 4 + 2], sc_s[c + 2], sh_s[c + 2]), 0.f);
                o.w = fmaxf(fmaf(acc[rr][j * 4 + 3], sc_s[c + 3], sh_s[c + 3]), 0.f);
                *(float4*)&orow[c] = o;
            }
        }
    }
}

// ---------------------------------------------------------------------------
// logits = in @ W[128,10] + b; out = log_softmax(logits). One row per wave.
__global__ __launch_bounds__(256) void head_kernel(
    const float* __restrict__ in, const float* __restrict__ W,
    const float* __restrict__ b, float* __restrict__ out, int N) {
    __shared__ float Wl[128 * 10];
    __shared__ float bl[10];
    for (int i = threadIdx.x; i < 1280; i += blockDim.x) Wl[i] = W[i];
    if (threadIdx.x < 10) bl[threadIdx.x] = b[threadIdx.x];
    __syncthreads();
    int wave = threadIdx.x >> 6;
    int lane = threadIdx.x & 63;
    int wid = blockIdx.x * 4 + wave;
    int nw = gridDim.x * 4;
    for (int row = wid; row < N; row += nw) {
        const float* ir = in + (long long)row * 128;
        float h0 = ir[lane];
        float h1 = ir[lane + 64];
        float logit[10];
#pragma unroll
        for (int c = 0; c < 10; ++c) {
            float p = h0 * Wl[lane * 10 + c] + h1 * Wl[(lane + 64) * 10 + c];
#pragma unroll
            for (int off = 32; off > 0; off >>= 1) p += __shfl_down(p, off);
            logit[c] = p;  // valid on lane 0
        }
        if (lane == 0) {
            float mx = -1e30f;
#pragma unroll
            for (int c = 0; c < 10; ++c) {
                logit[c] += bl[c];
                mx = fmaxf(mx, logit[c]);
            }
            float sum = 0.f;
#pragma unroll
            for (int c = 0; c < 10; ++c) sum += expf(logit[c] - mx);
            float lse = mx + logf(sum);
            float* orow = out + (long long)row * 10;
#pragma unroll
            for (int c = 0; c < 10; ++c) orow[c] = logit[c] - lse;
        }
    }
}

// ---------------------------------------------------------------------------
extern "C" void kernel_launch(void* const* d_in, const int* in_sizes, int n_in,
                              void* d_out, int out_size, void* d_ws, size_t ws_size,
                              hipStream_t stream) {
    const float* x   = (const float*)d_in[0];
    const void*  eix = d_in[1];
    const float* eps = (const float*)d_in[2];
    const float* W1  = (const float*)d_in[3];
    const float* b1  = (const float*)d_in[4];
    const float* g1  = (const float*)d_in[5];
    const float* bb1 = (const float*)d_in[6];
    const float* m1  = (const float*)d_in[7];
    const float* v1  = (const float*)d_in[8];
    const float* W2  = (const float*)d_in[9];
    const float* b2  = (const float*)d_in[10];
    const float* g2  = (const float*)d_in[11];
    const float* bb2 = (const float*)d_in[12];
    const float* m2  = (const float*)d_in[13];
    const float* v2  = (const float*)d_in[14];
    const float* l1W = (const float*)d_in[15];
    const float* l1b = (const float*)d_in[16];
    const float* l2W = (const float*)d_in[17];
    const float* l2b = (const float*)d_in[18];

    const int N = in_sizes[0] / 128;
    const long long E = in_sizes[1] / 2;

    // workspace layout
    float* bufA = (float*)d_ws;                        // N*128 f32
    float* bufB = bufA + (size_t)N * 128;              // N*128 f32
    int* deg     = (int*)(bufB + (size_t)N * 128);     // N
    int* row_ptr = deg + N;                            // N+1
    int* cursor  = row_ptr + N + 1;                    // N
    int* csr_src = cursor + N;                         // E
    int* flag    = csr_src + E;                        // 1
    int* partial = flag + 1;                           // SCAN_BLOCKS

    detect_idx_kernel<<<1, 256, 0, stream>>>((const unsigned int*)eix,
                                             (E < 2048 ? E : 2048), flag);
    hipMemsetAsync(deg, 0, (size_t)N * sizeof(int), stream);

    const int eBlocks = 2048;
    hist_kernel<<<eBlocks, 256, 0, stream>>>(eix, E, flag, deg);
    scan_reduce_kernel<<<SCAN_BLOCKS, 256, 0, stream>>>(deg, N, partial);
    scan_partials_kernel<<<1, SCAN_BLOCKS, 0, stream>>>(partial, row_ptr, N, E);
    scan_write_kernel<<<SCAN_BLOCKS, 256, 0, stream>>>(deg, N, partial, row_ptr, cursor);
    fill_kernel<<<eBlocks, 256, 0, stream>>>(eix, E, flag, cursor, csr_src);

    const int gBlocks = 2048;                 // gather: 8192 waves grid-stride
    const int mBlocks = (N + 255) / 256;      // gemm tiles

    const float* cur = x;
    float* nxt = bufA;
    float* other = bufB;
    for (int l = 0; l < 3; ++l) {
        gather_kernel<<<gBlocks, 256, 0, stream>>>(nxt, cur, row_ptr, csr_src, eps, l, N);
        gemm_bn_relu_kernel<<<mBlocks, 256, 0, stream>>>(
            nxt, W1 + (size_t)l * 16384, b1 + l * 128, g1 + l * 128, bb1 + l * 128,
            m1 + l * 128, v1 + l * 128, nxt, N);
        gemm_bn_relu_kernel<<<mBlocks, 256, 0, stream>>>(
            nxt, W2 + (size_t)l * 16384, b2 + l * 128, g2 + l * 128, bb2 + l * 128,
            m2 + l * 128, v2 + l * 128, nxt, N);
        cur = nxt;
        nxt = other;
        other = (float*)cur;
    }
    // lin1 + ReLU (no BN): scale=1, shift=bias
    gemm_bn_relu_kernel<<<mBlocks, 256, 0, stream>>>(
        cur, l1W, l1b, nullptr, nullptr, nullptr, nullptr, nxt, N);
    // lin2 + log_softmax
    head_kernel<<<4096, 256, 0, stream>>>(nxt, l2W, l2b, (float*)d_out, N);
}

// Round 5
// 612.932 us; speedup vs baseline: 19.3097x; 1.6252x over previous
//
#include <hip/hip_runtime.h>
#include <hip/hip_fp16.h>

// GIN: 3 layers of {CSR-gather aggregate fused with (1+eps)*x, MLP(2x GEMM128 + BN + ReLU)},
// then lin1(128->128)+ReLU, lin2(128->10), log_softmax.
// N=100000, E=1.6M. Round 5: fp16 activations + fp16 MFMA GEMMs (fp32 accumulate).

#define SCAN_BLOCKS 256

typedef _Float16 f16x8 __attribute__((ext_vector_type(8)));
typedef float f32x4 __attribute__((ext_vector_type(4)));

struct H4 { __half2 a, b; };   // 8B fp16 quad

// ---------------------------------------------------------------------------
// Detect whether edge_index is int64 (all high words zero) or int32.
__global__ void detect_idx_kernel(const unsigned int* __restrict__ w, long long nOdd,
                                  int* __restrict__ flag) {
    __shared__ int any;
    if (threadIdx.x == 0) any = 0;
    __syncthreads();
    for (long long i = threadIdx.x; i < nOdd; i += blockDim.x) {
        if (w[2 * i + 1] != 0u) { any = 1; break; }
    }
    __syncthreads();
    if (threadIdx.x == 0) *flag = (any == 0) ? 1 : 0;   // 1 => int64 layout
}

// ---------------------------------------------------------------------------
__global__ void hist_kernel(const void* __restrict__ idx, long long E,
                            const int* __restrict__ flag, int* __restrict__ deg) {
    long long i = (long long)blockIdx.x * blockDim.x + threadIdx.x;
    long long stride = (long long)gridDim.x * blockDim.x;
    if (*flag) {
        const long long* p = (const long long*)idx + E;   // dst half
        for (; i < E; i += stride) atomicAdd(&deg[(int)p[i]], 1);
    } else {
        const int* p = (const int*)idx + E;
        for (; i < E; i += stride) atomicAdd(&deg[p[i]], 1);
    }
}

// ---------------------------------------------------------------------------
__global__ __launch_bounds__(256) void scan_reduce_kernel(const int* __restrict__ deg,
                                                          int N, int* __restrict__ partial) {
    int b = blockIdx.x, t = threadIdx.x;
    int C = (N + SCAN_BLOCKS - 1) / SCAN_BLOCKS;
    int lo = b * C, hi = lo + C; if (hi > N) hi = N;
    int s = 0;
    for (int i = lo + t; i < hi; i += 256) s += deg[i];
    __shared__ int red[256];
    red[t] = s;
    __syncthreads();
    for (int off = 128; off > 0; off >>= 1) {
        if (t < off) red[t] += red[t + off];
        __syncthreads();
    }
    if (t == 0) partial[b] = red[0];
}

__global__ __launch_bounds__(256) void scan_partials_kernel(int* __restrict__ partial,
                                                            int* __restrict__ row_ptr,
                                                            int N, long long E) {
    int t = threadIdx.x;
    __shared__ int sh[SCAN_BLOCKS];
    sh[t] = partial[t];
    __syncthreads();
    for (int off = 1; off < SCAN_BLOCKS; off <<= 1) {
        int v = (t >= off) ? sh[t - off] : 0;
        __syncthreads();
        sh[t] += v;
        __syncthreads();
    }
    partial[t] = (t == 0) ? 0 : sh[t - 1];   // exclusive
    if (t == 0) row_ptr[N] = (int)E;
}

__global__ __launch_bounds__(256) void scan_write_kernel(const int* __restrict__ deg, int N,
                                                         const int* __restrict__ partial,
                                                         int* __restrict__ row_ptr,
                                                         int* __restrict__ cursor) {
    int b = blockIdx.x, t = threadIdx.x;
    int C = (N + SCAN_BLOCKS - 1) / SCAN_BLOCKS;
    int lo = b * C, hi = lo + C; if (hi > N) hi = N;
    int sub = (C + 255) / 256;
    int s0 = lo + t * sub;
    int s1 = s0 + sub; if (s1 > hi) s1 = hi; if (s0 > hi) s0 = hi;
    int s = 0;
    for (int i = s0; i < s1; ++i) s += deg[i];
    __shared__ int sh[256];
    sh[t] = s;
    __syncthreads();
    for (int off = 1; off < 256; off <<= 1) {
        int v = (t >= off) ? sh[t - off] : 0;
        __syncthreads();
        sh[t] += v;
        __syncthreads();
    }
    int base = partial[b] + sh[t] - s;
    for (int i = s0; i < s1; ++i) {
        row_ptr[i] = base;
        cursor[i] = base;
        base += deg[i];
    }
}

// ---------------------------------------------------------------------------
__global__ void fill_kernel(const void* __restrict__ idx, long long E,
                            const int* __restrict__ flag, int* __restrict__ cursor,
                            int* __restrict__ csr_src) {
    long long i = (long long)blockIdx.x * blockDim.x + threadIdx.x;
    long long stride = (long long)gridDim.x * blockDim.x;
    if (*flag) {
        const long long* ps = (const long long*)idx;
        const long long* pd = ps + E;
        for (; i < E; i += stride) {
            int pos = atomicAdd(&cursor[(int)pd[i]], 1);
            csr_src[pos] = (int)ps[i];
        }
    } else {
        const int* ps = (const int*)idx;
        const int* pd = ps + E;
        for (; i < E; i += stride) {
            int pos = atomicAdd(&cursor[pd[i]], 1);
            csr_src[pos] = ps[i];
        }
    }
}

// ---------------------------------------------------------------------------
// x fp32 [N,128] -> fp16. Each thread: 4 floats -> 4 halves (8B store).
__global__ void convert_x_kernel(__half* __restrict__ out, const float* __restrict__ in,
                                 int n4) {
    int i = blockIdx.x * blockDim.x + threadIdx.x;
    int stride = gridDim.x * blockDim.x;
    const float4* in4 = (const float4*)in;
    for (; i < n4; i += stride) {
        float4 v = in4[i];
        H4 h;
        h.a = __float22half2_rn(make_float2(v.x, v.y));
        h.b = __float22half2_rn(make_float2(v.z, v.w));
        *(H4*)(out + i * 4) = h;
    }
}

// ---------------------------------------------------------------------------
// Pack 7 fp32 [128][128] weight matrices (W1 l0..2, W2 l0..2, lin1) into fp16
// MFMA "A-operand" fragment order: pk[mat][((ks*8+ct)*64+lane)*8 + j] =
//   W[ks*32 + (lane>>4)*8 + j][ct*16 + (lane&15)]
__global__ void pack_w_kernel(__half* __restrict__ pk, const float* __restrict__ W1,
                              const float* __restrict__ W2, const float* __restrict__ lin1) {
    int t = blockIdx.x * blockDim.x + threadIdx.x;
    if (t >= 7 * 2048) return;
    int mat = t >> 11;
    int rem = t & 2047;
    int ks = rem >> 9;
    int ct = (rem >> 6) & 7;
    int lane = rem & 63;
    int g = lane >> 4, c = lane & 15;
    const float* src = (mat < 3) ? W1 + mat * 16384
                     : (mat < 6) ? W2 + (mat - 3) * 16384
                                 : lin1;
    __half* dst = pk + mat * 16384 + ((size_t)((ks * 8 + ct) * 64 + lane)) * 8;
#pragma unroll
    for (int j = 0; j < 8; ++j)
        dst[j] = (__half)src[(ks * 32 + g * 8 + j) * 128 + ct * 16 + c];
}

// ---------------------------------------------------------------------------
// out[n] = fp16( (1+eps)*x[n] + sum_j x[csr[j]] ), fp32 accumulate.
// One wave per node, half2 per lane, unroll x4.
__global__ __launch_bounds__(256) void gather_h_kernel(
    __half* __restrict__ out, const __half* __restrict__ x,
    const int* __restrict__ row_ptr, const int* __restrict__ csr,
    const float* __restrict__ eps, int layer, int N) {
    int wave = threadIdx.x >> 6;
    int lane = threadIdx.x & 63;
    int wid = blockIdx.x * 4 + wave;
    int nw = gridDim.x * 4;
    float s = 1.0f + eps[layer];
    for (int n = wid; n < N; n += nw) {
        float2 acc = __half22float2(((const __half2*)(x + n * 128))[lane]);
        acc.x *= s; acc.y *= s;
        int beg = row_ptr[n], end = row_ptr[n + 1];
        int j = beg;
        for (; j + 3 < end; j += 4) {
            int s0 = csr[j], s1 = csr[j + 1], s2 = csr[j + 2], s3 = csr[j + 3];
            float2 v0 = __half22float2(((const __half2*)(x + s0 * 128))[lane]);
            float2 v1 = __half22float2(((const __half2*)(x + s1 * 128))[lane]);
            float2 v2 = __half22float2(((const __half2*)(x + s2 * 128))[lane]);
            float2 v3 = __half22float2(((const __half2*)(x + s3 * 128))[lane]);
            acc.x += (v0.x + v1.x) + (v2.x + v3.x);
            acc.y += (v0.y + v1.y) + (v2.y + v3.y);
        }
        for (; j < end; ++j) {
            float2 v = __half22float2(((const __half2*)(x + csr[j] * 128))[lane]);
            acc.x += v.x;
            acc.y += v.y;
        }
        ((__half2*)(out + n * 128))[lane] = __float22half2_rn(acc);
    }
}

// ---------------------------------------------------------------------------
// out = relu(BN(in @ W + bias)) via MFMA f16. 128 rows/block, 256 thr (4 waves
// x 32 rows). A staged whole-K in LDS with XOR-swizzled 16B chunks; W read as
// pre-packed frags from global (L2-resident). Operands swapped (mfma(W,act))
// so each lane's C frag = 4 consecutive cols of one row -> 8B fp16 stores.
// g == nullptr: scale=1, shift=bias. In-place safe (block reads own rows only).
__global__ __launch_bounds__(256) void gemm_h_kernel(
    const __half* __restrict__ in, const __half* __restrict__ pk,
    const float* __restrict__ bias, const float* __restrict__ g,
    const float* __restrict__ bb, const float* __restrict__ m,
    const float* __restrict__ vv, __half* __restrict__ out, int N) {
    __shared__ __half sA[128 * 128];
    __shared__ float sc_s[128];
    __shared__ float sh_s[128];

    const int tid = threadIdx.x;
    if (tid < 128) {
        int c = tid;
        float sc, sh;
        if (g != nullptr) {
            sc = g[c] * rsqrtf(vv[c] + 1e-5f);
            sh = bias[c] * sc + bb[c] - m[c] * sc;
        } else {
            sc = 1.0f;
            sh = bias[c];
        }
        sc_s[c] = sc;
        sh_s[c] = sh;
    }

    const int base = blockIdx.x * 128;
    // stage 128 rows x 128 fp16 (16B chunks, chunk idx XOR row&15)
#pragma unroll
    for (int q = 0; q < 8; ++q) {
        int i = tid + q * 256;          // 0..2047 chunks
        int row = i >> 4, c = i & 15;
        int r = base + row;
        if (r >= N) r = N - 1;
        uint4 v = *(const uint4*)(in + r * 128 + c * 8);
        *(uint4*)&sA[row * 128 + ((c ^ (row & 15)) * 8)] = v;
    }
    __syncthreads();

    const int wave = tid >> 6;
    const int lane = tid & 63;
    const int g16 = lane >> 4;
    const int r15 = lane & 15;

    f32x4 acc[2][8];
#pragma unroll
    for (int rt = 0; rt < 2; ++rt)
#pragma unroll
        for (int ct = 0; ct < 8; ++ct) acc[rt][ct] = (f32x4)0.f;

#pragma unroll
    for (int ks = 0; ks < 4; ++ks) {
        f16x8 wf[8];
#pragma unroll
        for (int ct = 0; ct < 8; ++ct)
            wf[ct] = *(const f16x8*)(pk + ((ks * 8 + ct) * 64 + lane) * 8);
#pragma unroll
        for (int rt = 0; rt < 2; ++rt) {
            int row = wave * 32 + rt * 16 + r15;
            f16x8 bf = *(const f16x8*)&sA[row * 128 + (((ks * 4 + g16) ^ r15) * 8)];
#pragma unroll
            for (int ct = 0; ct < 8; ++ct)
                acc[rt][ct] = __builtin_amdgcn_mfma_f32_16x16x32_f16(wf[ct], bf,
                                                                     acc[rt][ct], 0, 0, 0);
        }
    }

    // epilogue: lane writes cols [ct*16+g16*4, +4) of row (base+wave*32+rt*16+r15)
#pragma unroll
    for (int rt = 0; rt < 2; ++rt) {
        int r = base + wave * 32 + rt * 16 + r15;
        if (r < N) {
            __half* orow = out + r * 128;
#pragma unroll
            for (int ct = 0; ct < 8; ++ct) {
                int col = ct * 16 + g16 * 4;
                float4 sc4 = *(float4*)&sc_s[col];
                float4 sh4 = *(float4*)&sh_s[col];
                f32x4 a = acc[rt][ct];
                float o0 = fmaxf(fmaf(a[0], sc4.x, sh4.x), 0.f);
                float o1 = fmaxf(fmaf(a[1], sc4.y, sh4.y), 0.f);
                float o2 = fmaxf(fmaf(a[2], sc4.z, sh4.z), 0.f);
                float o3 = fmaxf(fmaf(a[3], sc4.w, sh4.w), 0.f);
                H4 h;
                h.a = __float22half2_rn(make_float2(o0, o1));
                h.b = __float22half2_rn(make_float2(o2, o3));
                *(H4*)(orow + col) = h;
            }
        }
    }
}

// ---------------------------------------------------------------------------
// logits = in(fp16) @ W[128,10] + b; out = log_softmax (fp32). One row/wave.
__global__ __launch_bounds__(256) void head_kernel(
    const __half* __restrict__ in, const float* __restrict__ W,
    const float* __restrict__ b, float* __restrict__ out, int N) {
    __shared__ float Wl[128 * 10];
    __shared__ float bl[10];
    for (int i = threadIdx.x; i < 1280; i += blockDim.x) Wl[i] = W[i];
    if (threadIdx.x < 10) bl[threadIdx.x] = b[threadIdx.x];
    __syncthreads();
    int wave = threadIdx.x >> 6;
    int lane = threadIdx.x & 63;
    int wid = blockIdx.x * 4 + wave;
    int nw = gridDim.x * 4;
    for (int row = wid; row < N; row += nw) {
        float2 f = __half22float2(((const __half2*)(in + row * 128))[lane]);
        float logit[10];
#pragma unroll
        for (int c = 0; c < 10; ++c) {
            float p = f.x * Wl[(2 * lane) * 10 + c] + f.y * Wl[(2 * lane + 1) * 10 + c];
#pragma unroll
            for (int off = 32; off > 0; off >>= 1) p += __shfl_down(p, off);
            logit[c] = p;
        }
        if (lane == 0) {
            float mx = -1e30f;
#pragma unroll
            for (int c = 0; c < 10; ++c) {
                logit[c] += bl[c];
                mx = fmaxf(mx, logit[c]);
            }
            float sum = 0.f;
#pragma unroll
            for (int c = 0; c < 10; ++c) sum += expf(logit[c] - mx);
            float lse = mx + logf(sum);
            float* orow = out + (long long)row * 10;
#pragma unroll
            for (int c = 0; c < 10; ++c) orow[c] = logit[c] - lse;
        }
    }
}

// ---------------------------------------------------------------------------
extern "C" void kernel_launch(void* const* d_in, const int* in_sizes, int n_in,
                              void* d_out, int out_size, void* d_ws, size_t ws_size,
                              hipStream_t stream) {
    const float* x   = (const float*)d_in[0];
    const void*  eix = d_in[1];
    const float* eps = (const float*)d_in[2];
    const float* W1  = (const float*)d_in[3];
    const float* b1  = (const float*)d_in[4];
    const float* g1  = (const float*)d_in[5];
    const float* bb1 = (const float*)d_in[6];
    const float* m1  = (const float*)d_in[7];
    const float* v1  = (const float*)d_in[8];
    const float* W2  = (const float*)d_in[9];
    const float* b2  = (const float*)d_in[10];
    const float* g2  = (const float*)d_in[11];
    const float* bb2 = (const float*)d_in[12];
    const float* m2  = (const float*)d_in[13];
    const float* v2  = (const float*)d_in[14];
    const float* l1W = (const float*)d_in[15];
    const float* l1b = (const float*)d_in[16];
    const float* l2W = (const float*)d_in[17];
    const float* l2b = (const float*)d_in[18];

    const int N = in_sizes[0] / 128;
    const long long E = in_sizes[1] / 2;

    // workspace layout (fp16 buffers first, 16B-aligned)
    __half* bufA = (__half*)d_ws;                      // N*128 fp16
    __half* bufB = bufA + (size_t)N * 128;             // N*128 fp16
    __half* pk   = bufB + (size_t)N * 128;             // 7*16384 fp16
    int* deg     = (int*)(pk + 7 * 16384);             // N
    int* row_ptr = deg + N;                            // N+1
    int* cursor  = row_ptr + N + 1;                    // N
    int* csr_src = cursor + N;                         // E
    int* flag    = csr_src + E;                        // 1
    int* partial = flag + 1;                           // SCAN_BLOCKS

    detect_idx_kernel<<<1, 256, 0, stream>>>((const unsigned int*)eix,
                                             (E < 2048 ? E : 2048), flag);
    hipMemsetAsync(deg, 0, (size_t)N * sizeof(int), stream);

    const int eBlocks = 2048;
    hist_kernel<<<eBlocks, 256, 0, stream>>>(eix, E, flag, deg);
    scan_reduce_kernel<<<SCAN_BLOCKS, 256, 0, stream>>>(deg, N, partial);
    scan_partials_kernel<<<1, SCAN_BLOCKS, 0, stream>>>(partial, row_ptr, N, E);
    scan_write_kernel<<<SCAN_BLOCKS, 256, 0, stream>>>(deg, N, partial, row_ptr, cursor);
    fill_kernel<<<eBlocks, 256, 0, stream>>>(eix, E, flag, cursor, csr_src);

    convert_x_kernel<<<2048, 256, 0, stream>>>(bufA, x, N * 32);
    pack_w_kernel<<<(7 * 2048 + 255) / 256, 256, 0, stream>>>(pk, W1, W2, l1W);

    const int gBlocks = 2048;
    const int mBlocks = (N + 127) / 128;

    __half* cur = bufA;
    __half* oth = bufB;
    for (int l = 0; l < 3; ++l) {
        gather_h_kernel<<<gBlocks, 256, 0, stream>>>(oth, cur, row_ptr, csr_src, eps, l, N);
        gemm_h_kernel<<<mBlocks, 256, 0, stream>>>(
            oth, pk + (size_t)l * 16384, b1 + l * 128, g1 + l * 128, bb1 + l * 128,
            m1 + l * 128, v1 + l * 128, oth, N);
        gemm_h_kernel<<<mBlocks, 256, 0, stream>>>(
            oth, pk + (size_t)(3 + l) * 16384, b2 + l * 128, g2 + l * 128, bb2 + l * 128,
            m2 + l * 128, v2 + l * 128, oth, N);
        __half* t = cur; cur = oth; oth = t;
    }
    // lin1 + ReLU (no BN)
    gemm_h_kernel<<<mBlocks, 256, 0, stream>>>(
        cur, pk + (size_t)6 * 16384, l1b, nullptr, nullptr, nullptr, nullptr, oth, N);
    // lin2 + log_softmax
    head_kernel<<<4096, 256, 0, stream>>>(oth, l2W, l2b, (float*)d_out, N);
}